// Round 4
// baseline (120.673 us; speedup 1.0000x reference)
//
#include <hip/hip_runtime.h>
#include <hip/hip_bf16.h>

#define K 128
#define NB 4096
#define STRIDE 130     // ushorts per COLUMN of Mh (column-major); gather reads are conflict-free
#define FW_ITERS 50

// VALU-only reduce steps via DPP (quad_perm / row_ror within 16-lane rows)
template<int CTRL>
__device__ __forceinline__ float dpp_fmin(float v) {
    int s = __builtin_amdgcn_update_dpp(__float_as_int(v), __float_as_int(v), CTRL, 0xF, 0xF, false);
    return fminf(v, __int_as_float(s));
}
template<int CTRL>
__device__ __forceinline__ float dpp_fadd(float v) {
    int s = __builtin_amdgcn_update_dpp(__float_as_int(v), __float_as_int(v), CTRL, 0xF, 0xF, false);
    return v + __int_as_float(s);
}

// 64-lane min of v, result in all lanes (proven exact in round 3: absmax 0.0)
__device__ __forceinline__ float wave_fmin_all(float v) {
    v = dpp_fmin<0xB1>(v);   // quad_perm xor1
    v = dpp_fmin<0x4E>(v);   // quad_perm xor2
    v = dpp_fmin<0x124>(v);  // row_ror:4
    v = dpp_fmin<0x128>(v);  // row_ror:8 -> per-16 min
#if __has_builtin(__builtin_amdgcn_permlane16_swap)
    {
        auto r = __builtin_amdgcn_permlane16_swap(__float_as_int(v), __float_as_int(v), false, false);
        v = fminf(__int_as_float(r[0]), __int_as_float(r[1]));
    }
#else
    v = fminf(v, __shfl_xor(v, 16, 64));
#endif
#if __has_builtin(__builtin_amdgcn_permlane32_swap)
    {
        auto r = __builtin_amdgcn_permlane32_swap(__float_as_int(v), __float_as_int(v), false, false);
        v = fminf(__int_as_float(r[0]), __int_as_float(r[1]));
    }
#else
    v = fminf(v, __shfl_xor(v, 32, 64));
#endif
    return v;
}

// sum over each 32-lane half (lanes 0-31 and 32-63 independently), result in all lanes
__device__ __forceinline__ float half_sum32(float v) {
    v = dpp_fadd<0xB1>(v);
    v = dpp_fadd<0x4E>(v);
    v = dpp_fadd<0x124>(v);
    v = dpp_fadd<0x128>(v);   // per-16 sum
#if __has_builtin(__builtin_amdgcn_permlane16_swap)
    {
        auto r = __builtin_amdgcn_permlane16_swap(__float_as_int(v), __float_as_int(v), false, false);
        v = __int_as_float(r[0]) + __int_as_float(r[1]);
    }
#else
    v = v + __shfl_xor(v, 16, 64);
#endif
    return v;
}

__device__ __forceinline__ unsigned short bf16_bits(float f) {
    __hip_bfloat16 h = __float2bfloat16(f);
    return *reinterpret_cast<unsigned short*>(&h);
}

__global__ __launch_bounds__(256) void cacis_main(
    const float* __restrict__ scores,
    const float* __restrict__ C,
    const int* __restrict__ targets,
    float* __restrict__ out_partial)
{
    __shared__ float s_lds[2][K];
    __shared__ float alpha[2][K];
    __shared__ float grow[2][K];
    __shared__ unsigned short Mh[2][K * STRIDE];   // column-major: Mh[e][col*STRIDE + row]
    __shared__ float red[4][4];

    const int b = blockIdx.x;          // 0..NB/2-1
    const int tid = threadIdx.x;
    const int w = tid >> 6;
    const int lane = tid & 63;
    const int cbase = 4 * (tid & 31);

    float eps_e[2], minv_e[2];

    // ---- phase 1: load + reduce + M build, examples e=0,1 sequentially ----
    for (int e = 0; e < 2; ++e) {
        const int ex = 2 * b + e;
        if (tid < K) s_lds[e][tid] = scores[ex * K + tid];
        __syncthreads();

        const float* Cb = C + (size_t)ex * (K * K);
        float4 c[16];
        #pragma unroll
        for (int j = 0; j < 16; ++j)
            c[j] = *reinterpret_cast<const float4*>(Cb + 4 * tid + 1024 * j);

        float sc[4];
        {
            float4 s4 = *reinterpret_cast<const float4*>(&s_lds[e][cbase]);
            sc[0] = s4.x; sc[1] = s4.y; sc[2] = s4.z; sc[3] = s4.w;
        }

        float sumC = 0.f, trace = 0.f, minv = 1e30f;
        #pragma unroll
        for (int j = 0; j < 16; ++j) {
            const int row = 8 * j + (tid >> 5);
            const float sr = s_lds[e][row];
            float4 v = c[j];
            sumC += (v.x + v.y) + (v.z + v.w);
            const int d = row - cbase;
            if (d >= 0 && d < 4)
                trace += (d == 0) ? v.x : (d == 1) ? v.y : (d == 2) ? v.z : v.w;
            float t0 = sr + sc[0] + v.x;
            float t1 = sr + sc[1] + v.y;
            float t2 = sr + sc[2] + v.z;
            float t3 = sr + sc[3] + v.w;
            c[j] = make_float4(t0, t1, t2, t3);
            minv = fminf(minv, fminf(fminf(t0, t1), fminf(t2, t3)));
        }

        #pragma unroll
        for (int m = 1; m < 64; m <<= 1) {
            sumC  += __shfl_xor(sumC, m, 64);
            trace += __shfl_xor(trace, m, 64);
            minv   = fminf(minv, __shfl_xor(minv, m, 64));
        }
        if (lane == 0) { red[w][0] = sumC; red[w][1] = trace; red[w][2] = minv; }
        __syncthreads();
        sumC  = (red[0][0] + red[1][0]) + (red[2][0] + red[3][0]);
        trace = (red[0][1] + red[1][1]) + (red[2][1] + red[3][1]);
        minv  = fminf(fminf(red[0][2], red[1][2]), fminf(red[2][2], red[3][2]));

        float eps = (sumC - trace) * (1.0f / (float)(K * (K - 1)));
        eps = fmaxf(eps, 1e-8f);              // EPS_SCALE = 1.0
        const float inv_eps = 1.0f / eps;
        eps_e[e] = eps; minv_e[e] = minv;

        // M = exp((minv - t)/eps): bf16 column-major to LDS + fp32 in-register rowsum
        #pragma unroll
        for (int j = 0; j < 16; ++j) {
            const int row = 8 * j + (tid >> 5);
            float4 v = c[j];
            float m0 = __expf((minv - v.x) * inv_eps);
            float m1 = __expf((minv - v.y) * inv_eps);
            float m2 = __expf((minv - v.z) * inv_eps);
            float m3 = __expf((minv - v.w) * inv_eps);
            Mh[e][(cbase + 0) * STRIDE + row] = bf16_bits(m0);
            Mh[e][(cbase + 1) * STRIDE + row] = bf16_bits(m1);
            Mh[e][(cbase + 2) * STRIDE + row] = bf16_bits(m2);
            Mh[e][(cbase + 3) * STRIDE + row] = bf16_bits(m3);
            // lanes 0-31 of the wave hold the full row 'row'; lanes 32-63 hold row+1's data
            float rs = half_sum32((m0 + m1) + (m2 + m3));
            if ((lane & 31) == 0) grow[e][row] = rs * (1.0f / (float)K);
        }
        __syncthreads();   // Mh[e], grow[e] visible; also fences red[] reuse
    }

    // ---- phase 2: dual Frank-Wolfe chains (wave 0 -> e0, wave 1 -> e1) ----
    // h' = (1-step)*h + step*M[:,idx]; it=0 step=1 resets FP state exactly
    if (w < 2) {
        const unsigned short* mb = &Mh[w][0];
        float g0 = grow[w][2 * lane], g1 = grow[w][2 * lane + 1];
        float a0 = 1.0f / K, a1 = 1.0f / K;
        #pragma unroll 1
        for (int it = 0; it < FW_ITERS; ++it) {
            const float v = wave_fmin_all(fminf(g0, g1));
            unsigned long long b0 = __ballot(g0 == v);
            unsigned long long b1 = __ballot(g1 == v);
            int i0 = b0 ? 2 * (int)__builtin_ctzll(b0)     : 0x7fffffff;
            int i1 = b1 ? 2 * (int)__builtin_ctzll(b1) + 1 : 0x7fffffff;
            const int idx = min(i0, i1);    // first-index tie-break

            const float step = 2.0f / (float)(it + 2);
            const float om = 1.0f - step;
            a0 *= om; a1 *= om;
            if (2 * lane == idx)     a0 += step;
            if (2 * lane + 1 == idx) a1 += step;
            // one conflict-free b32 read yields M[2*lane][idx] and M[2*lane+1][idx]
            unsigned int u = *reinterpret_cast<const unsigned int*>(&mb[idx * STRIDE + 2 * lane]);
            float c0 = __uint_as_float(u << 16);
            float c1 = __uint_as_float(u & 0xffff0000u);
            g0 = om * g0 + step * c0;
            g1 = om * g1 + step * c1;
        }
        alpha[w][2 * lane]     = a0;
        alpha[w][2 * lane + 1] = a1;
    }
    __syncthreads();

    // ---- phase 3: val = alpha^T M alpha from bf16 LDS (column-owner scheme) ----
    for (int e = 0; e < 2; ++e) {
        const int col = tid >> 1;
        const int rh  = tid & 1;
        const unsigned short* cp = &Mh[e][col * STRIDE + rh * 64];
        const float ac = alpha[e][col];
        float acc = 0.f;
        #pragma unroll
        for (int k = 0; k < 32; ++k) {
            unsigned int u = *reinterpret_cast<const unsigned int*>(&cp[2 * k]);
            float m0 = __uint_as_float(u << 16);
            float m1 = __uint_as_float(u & 0xffff0000u);
            acc += alpha[e][rh * 64 + 2 * k] * m0 + alpha[e][rh * 64 + 2 * k + 1] * m1;
        }
        float valp = acc * ac;
        #pragma unroll
        for (int m = 1; m < 64; m <<= 1) valp += __shfl_xor(valp, m, 64);
        if (lane == 0) red[w][0] = valp;
        __syncthreads();
        if (tid == 0) {
            const float val = (red[0][0] + red[1][0]) + (red[2][0] + red[3][0]);
            // conjugate = -eps*(log(val+1e-12) + shift), shift = -minv/eps -> -eps*log(..) + minv
            const float conj = -eps_e[e] * logf(val + 1e-12f) + minv_e[e];
            const int tgt = targets[2 * b + e];
            out_partial[2 * b + e] = conj - s_lds[e][tgt];
        }
        __syncthreads();   // fence red[] reuse for e=1
    }
}

__global__ __launch_bounds__(256) void cacis_reduce(
    const float* __restrict__ part, float* __restrict__ out)
{
    __shared__ float red[4];
    const int tid = threadIdx.x;
    float acc = 0.f;
    for (int i = tid; i < NB; i += 256) acc += part[i];
    #pragma unroll
    for (int m = 1; m < 64; m <<= 1) acc += __shfl_xor(acc, m, 64);
    if ((tid & 63) == 0) red[tid >> 6] = acc;
    __syncthreads();
    if (tid == 0) out[0] = ((red[0] + red[1]) + (red[2] + red[3])) * (1.0f / (float)NB);
}

extern "C" void kernel_launch(void* const* d_in, const int* in_sizes, int n_in,
                              void* d_out, int out_size, void* d_ws, size_t ws_size,
                              hipStream_t stream) {
    const float* scores  = (const float*)d_in[0];
    const float* C       = (const float*)d_in[1];
    const int*   targets = (const int*)d_in[2];
    float* out  = (float*)d_out;
    float* part = (float*)d_ws;   // NB floats = 16 KB

    cacis_main<<<NB / 2, 256, 0, stream>>>(scores, C, targets, part);
    cacis_reduce<<<1, 256, 0, stream>>>(part, out);
}